// Round 11
// baseline (184.328 us; speedup 1.0000x reference)
//
#include <hip/hip_runtime.h>

#define B_ 2
#define N_ 512
#define F_ 128
#define TJ 64       // j-rows per tile
#define MSTRIDE 136 // shorts per LDS row: 128 + 8 pad (16B-aligned rows)

typedef __attribute__((ext_vector_type(8))) short short8;
typedef __attribute__((ext_vector_type(4))) float floatx4;

__device__ __forceinline__ float fsilu(float x) {
    float e = __expf(-x);
    return x * __builtin_amdgcn_rcpf(1.0f + e);
}
// pack two floats to bf16 pair via v_perm_b32
__device__ __forceinline__ unsigned pack2(float a, float b) {
    return __builtin_amdgcn_perm(__float_as_uint(b) + 0x8000u,
                                 __float_as_uint(a) + 0x8000u, 0x07060302u);
}

// ---------------------------------------------------------------------------
// Prep (proven since R6): blocks [0,128): Hs/Ht (8 rows each);
// [128,144): weight A-frag pack; [144,146): msum.
// ---------------------------------------------------------------------------
__global__ __launch_bounds__(256) void egcl_prep(
        const float* __restrict__ h, const float* __restrict__ mask,
        const float* __restrict__ ew1, const float* __restrict__ ew2,
        const float* __restrict__ cw1,
        float* __restrict__ Hs, float* __restrict__ Ht,
        unsigned short* __restrict__ W2P, unsigned short* __restrict__ WcP,
        float* __restrict__ msum) {
    __shared__ float sh[8][F_];
    const int blk = blockIdx.x, tid = threadIdx.x;
    if (blk < 128) {
        const int r0 = blk * 8;
        const int col = tid & 127, half = tid >> 7;
#pragma unroll
        for (int rr = 0; rr < 4; ++rr) {
            int row = rr * 2 + half;
            sh[row][col] = h[(r0 + row) * F_ + col] * mask[r0 + row];
        }
        __syncthreads();
        const float* W = ew1 + half * F_ * F_ + col;
        float acc[8] = {0.f, 0.f, 0.f, 0.f, 0.f, 0.f, 0.f, 0.f};
#pragma unroll 8
        for (int k = 0; k < F_; ++k) {
            float w = W[k * F_];
#pragma unroll
            for (int r = 0; r < 8; ++r) acc[r] += sh[r][k] * w;
        }
        float* dst = half ? Ht : Hs;
#pragma unroll
        for (int r = 0; r < 8; ++r) dst[(r0 + r) * F_ + col] = acc[r];
    } else if (blk < 144) {
        const int wsel = (blk - 128) >> 3;
        const int mt = (blk - 128) & 7;
        const float* src = wsel ? cw1 : ew2;
        unsigned short* dst = wsel ? WcP : W2P;
        const int ln = tid & 63, kk = tid >> 6;       // kk 0..3
        const int qq = ln >> 4, ll = ln & 15;
#pragma unroll
        for (int rep = 0; rep < 2; ++rep) {
            const int krow = kk * 32 + qq * 8 + rep * 4;
            float f0 = src[(krow + 0) * F_ + mt * 16 + ll];
            float f1 = src[(krow + 1) * F_ + mt * 16 + ll];
            float f2 = src[(krow + 2) * F_ + mt * 16 + ll];
            float f3 = src[(krow + 3) * F_ + mt * 16 + ll];
            uint2 u = make_uint2(pack2(f0, f1), pack2(f2, f3));
            *(uint2*)(dst + ((mt * 4 + kk) * 64 + ln) * 8 + rep * 4) = u;
        }
    } else {
        const int bb = blk - 144;
        float v = mask[bb * N_ + tid] + mask[bb * N_ + 256 + tid];
        v += __shfl_xor(v, 1);  v += __shfl_xor(v, 2);
        v += __shfl_xor(v, 4);  v += __shfl_xor(v, 8);
        v += __shfl_xor(v, 16); v += __shfl_xor(v, 32);
        const int wave = tid >> 6, lane = tid & 63;
        if (lane == 0) sh[0][wave] = v;
        __syncthreads();
        if (tid == 0) msum[bb] = sh[0][0] + sh[0][1] + sh[0][2] + sh[0][3];
    }
}

// LDS layout (bytes) — total 76.0 KB, 2 blocks/CU. (R2 proved >64KB dynamic
// LDS works on this harness.)
#define L_M1   0        // 2 buf * 64*136*2 = 34816
#define L_MS   34816    // 2 buf * 17408 = 34816
#define L_HB   69632    // 512
#define L_W1R  70144    // 512
#define L_DJS  70656    // 4-ring * 64 * float4 = 4096
#define L_AGG  74752    // 512
#define L_HIN  75264    // 512
#define L_AGGT 75776    // 512
#define L_TL   76288    // 512
#define L_NP   76800    // 1024
#define L_CSW  77824    // 48
#define L_TOTAL 77872

// ---------------------------------------------------------------------------
// Main: 1024 blocks x 256 threads (4 waves); block = one (b,i). Wave wg owns
// fo slice [wg*32,wg*32+32) with weights in regs as MFMA A-operands.
// SINGLE barrier per tile: each segment runs GEMM2[p-1] + GEMM1[p] +
// m1build[p+1] on ring-buffered LDS (m1s x2, ms x2, djs x4) — heterogeneous
// MFMA/VALU/trans/LDS work per segment for intra-wave interleave.
// Coord-sum is linear in per-wave partial embed -> no embp, no cross-wave
// embed exchange.
//
// __launch_bounds__ 2nd-arg EMPIRICAL RULE (this toolchain, gfx950):
//   (512,4)/(256,4) -> 64-VGPR cap, catastrophic spill (R4/R6).
//   (512,2)/(256,2) -> 128/256 cap, no spill (R5: 124, R7: 100). Keep 2.
// ---------------------------------------------------------------------------
__global__ __launch_bounds__(256, 2) void egcl_main(
        const float* __restrict__ h, const float* __restrict__ coord,
        const float* __restrict__ mask,
        const float* __restrict__ eb1, const float* __restrict__ eb2,
        const float* __restrict__ cb1, const float* __restrict__ cw2,
        const float* __restrict__ nw1, const float* __restrict__ nb1,
        const float* __restrict__ nw2, const float* __restrict__ nb2,
        const float* __restrict__ ew1,
        const float* __restrict__ Hs, const float* __restrict__ Ht,
        const unsigned short* __restrict__ W2P,
        const unsigned short* __restrict__ WcP,
        const float* __restrict__ msum,
        float* __restrict__ out_h, float* __restrict__ out_coord) {
    extern __shared__ char smem[];
    unsigned short* m1s = (unsigned short*)(smem + L_M1);
    unsigned short* ms  = (unsigned short*)(smem + L_MS);
    float* HB    = (float*)(smem + L_HB);
    float* W1R   = (float*)(smem + L_W1R);
    float* djs   = (float*)(smem + L_DJS);    // ring[4][64]: d0,d1,d2,f2
    float* aggs  = (float*)(smem + L_AGG);
    float* hin   = (float*)(smem + L_HIN);
    float* aggt  = (float*)(smem + L_AGGT);
    float* tl    = (float*)(smem + L_TL);
    float* np    = (float*)(smem + L_NP);
    float* csw   = (float*)(smem + L_CSW);    // [4][3]

    const int tid  = threadIdx.x;
    const int wave = tid >> 6, lane = tid & 63;
    const int q = lane >> 4, l15 = lane & 15;
    const int wg = wave;                 // fo slice [wg*32, wg*32+32)
    const int bi = blockIdx.x;
    const int b  = bi >> 9;
    const float mask_i = mask[bi];

    // per-wave weight A-fragments (2 mt-slices of 16 fo each)
    short8 w2f[2][4], wcf[2][4];
#pragma unroll
    for (int s = 0; s < 2; ++s)
#pragma unroll
        for (int kk = 0; kk < 4; ++kk) {
            w2f[s][kk] = *(const short8*)(W2P + (((2 * wg + s) * 4 + kk) * 64 + lane) * 8);
            wcf[s][kk] = *(const short8*)(WcP + (((2 * wg + s) * 4 + kk) * 64 + lane) * 8);
        }
    floatx4 e2b[2], c1b[2], w2c[2];
#pragma unroll
    for (int s = 0; s < 2; ++s) {
        e2b[s] = *(const floatx4*)(eb2 + wg * 32 + s * 16 + q * 4);
        c1b[s] = *(const floatx4*)(cb1 + wg * 32 + s * 16 + q * 4);
        w2c[s] = *(const floatx4*)(cw2 + wg * 32 + s * 16 + q * 4);
    }

    if (tid < F_) {
        HB[tid]  = Ht[bi * F_ + tid] + eb1[tid];
        W1R[tid] = ew1[2 * F_ * F_ + tid];
        hin[tid] = h[bi * F_ + tid] * mask_i;
    }
    const float cmi0 = coord[bi * 3 + 0] * mask_i;
    const float cmi1 = coord[bi * 3 + 1] * mask_i;
    const float cmi2 = coord[bi * 3 + 2] * mask_i;
    __syncthreads();

    const int kseg = tid & 15, jq = tid >> 4;  // jq in [0,16)
    float hbk[8], w1k[8];
    {
        const floatx4* hp = (const floatx4*)(HB + kseg * 8);
        const floatx4* wp = (const floatx4*)(W1R + kseg * 8);
        floatx4 a = hp[0], bb2 = hp[1], cc = wp[0], dd = wp[1];
#pragma unroll
        for (int t = 0; t < 4; ++t) {
            hbk[t] = a[t]; hbk[4 + t] = bb2[t];
            w1k[t] = cc[t]; w1k[4 + t] = dd[t];
        }
    }
    floatx4 agg0 = {0.f, 0.f, 0.f, 0.f}, agg1 = {0.f, 0.f, 0.f, 0.f};
    float cs0 = 0.f, cs1 = 0.f, cs2 = 0.f;

    // ---- stage bodies ----
    auto m1build = [&](int pp) {
        unsigned short* dst = m1s + (pp & 1) * (TJ * MSTRIDE);
        float* dj = djs + (pp & 3) * (TJ * 4);
#pragma unroll
        for (int r = 0; r < 4; ++r) {
            int row = jq * 4 + r;
            int jg = b * N_ + pp * TJ + row;
            float mj = mask[jg];
            float c0 = coord[jg * 3 + 0] * mj;
            float c1 = coord[jg * 3 + 1] * mj;
            float c2 = coord[jg * 3 + 2] * mj;
            float d0 = cmi0 - c0, d1 = cmi1 - c1, d2 = cmi2 - c2;
            float f2 = mask_i * mj;
            float rad = (d0 * d0 + d1 * d1 + d2 * d2) * f2;
            if (kseg == 0) {
                floatx4 v = {d0, d1, d2, f2};
                *(floatx4*)(dj + row * 4) = v;
            }
            const floatx4* hsp = (const floatx4*)(Hs + jg * F_ + kseg * 8);
            floatx4 h0 = hsp[0], h1 = hsp[1];
            float x[8];
#pragma unroll
            for (int t = 0; t < 4; ++t) {
                x[t]     = fsilu(h0[t] + hbk[t]     + rad * w1k[t]);
                x[4 + t] = fsilu(h1[t] + hbk[4 + t] + rad * w1k[4 + t]);
            }
            union { short8 s8; unsigned u[4]; } pu;
            pu.u[0] = pack2(x[0], x[1]); pu.u[1] = pack2(x[2], x[3]);
            pu.u[2] = pack2(x[4], x[5]); pu.u[3] = pack2(x[6], x[7]);
            *(short8*)(dst + row * MSTRIDE + kseg * 8) = pu.s8;
        }
    };

    auto gemm1 = [&](int p) {
        const unsigned short* m1b = m1s + (p & 1) * (TJ * MSTRIDE);
        unsigned short* msb = ms + (p & 1) * (TJ * MSTRIDE);
        const float* djp = djs + (p & 3) * (TJ * 4);
#pragma unroll
        for (int jt = 0; jt < 4; ++jt) {
            const int jrow = jt * 16 + l15;
            const unsigned short* m1r = m1b + jrow * MSTRIDE;
            floatx4 a0 = e2b[0], a1 = e2b[1];  // bias-init
#pragma unroll
            for (int kk = 0; kk < 4; ++kk) {
                short8 bf = *(const short8*)(m1r + kk * 32 + q * 8);
                a0 = __builtin_amdgcn_mfma_f32_16x16x32_bf16(w2f[0][kk], bf, a0, 0, 0, 0);
                a1 = __builtin_amdgcn_mfma_f32_16x16x32_bf16(w2f[1][kk], bf, a1, 0, 0, 0);
            }
            const float f2 = djp[jrow * 4 + 3];
            float v0[4], v1[4];
#pragma unroll
            for (int rg = 0; rg < 4; ++rg) {
                v0[rg] = fsilu(a0[rg]) * f2;
                v1[rg] = fsilu(a1[rg]) * f2;
                agg0[rg] += v0[rg];
                agg1[rg] += v1[rg];
            }
            unsigned short* mr = msb + jrow * MSTRIDE + wg * 32 + q * 4;
            *(uint2*)(mr)      = make_uint2(pack2(v0[0], v0[1]), pack2(v0[2], v0[3]));
            *(uint2*)(mr + 16) = make_uint2(pack2(v1[0], v1[1]), pack2(v1[2], v1[3]));
        }
    };

    auto gemm2 = [&](int p) {
        const unsigned short* msb = ms + (p & 1) * (TJ * MSTRIDE);
        const float* djp = djs + (p & 3) * (TJ * 4);
#pragma unroll
        for (int jt = 0; jt < 4; ++jt) {
            const int jrow = jt * 16 + l15;
            const unsigned short* mr = msb + jrow * MSTRIDE;
            floatx4 a0 = c1b[0], a1 = c1b[1];
#pragma unroll
            for (int kk = 0; kk < 4; ++kk) {
                short8 bf = *(const short8*)(mr + kk * 32 + q * 8);
                a0 = __builtin_amdgcn_mfma_f32_16x16x32_bf16(wcf[0][kk], bf, a0, 0, 0, 0);
                a1 = __builtin_amdgcn_mfma_f32_16x16x32_bf16(wcf[1][kk], bf, a1, 0, 0, 0);
            }
            float es = 0.f;
#pragma unroll
            for (int rg = 0; rg < 4; ++rg) {
                es += fsilu(a0[rg]) * w2c[0][rg];
                es += fsilu(a1[rg]) * w2c[1][rg];
            }
            // coord-sum is linear in the per-wave partial embed: accumulate
            // directly, no cross-wave embed exchange needed.
            floatx4 dj4 = *(const floatx4*)(djp + jrow * 4);
            float w = es * dj4[3] * dj4[3];
            cs0 += dj4[0] * w;
            cs1 += dj4[1] * w;
            cs2 += dj4[2] * w;
        }
    };

    // ---- pipelined main loop: ONE barrier per tile ----
    m1build(0);
    __syncthreads();
    for (int p = 0; p < N_ / TJ; ++p) {
        if (p > 0) gemm2(p - 1);
        gemm1(p);
        if (p < N_ / TJ - 1) m1build(p + 1);
        __syncthreads();
    }
    gemm2(N_ / TJ - 1);

    // ---- reductions ----
    cs0 += __shfl_xor(cs0, 1); cs0 += __shfl_xor(cs0, 2);
    cs0 += __shfl_xor(cs0, 4); cs0 += __shfl_xor(cs0, 8);
    cs0 += __shfl_xor(cs0, 16); cs0 += __shfl_xor(cs0, 32);
    cs1 += __shfl_xor(cs1, 1); cs1 += __shfl_xor(cs1, 2);
    cs1 += __shfl_xor(cs1, 4); cs1 += __shfl_xor(cs1, 8);
    cs1 += __shfl_xor(cs1, 16); cs1 += __shfl_xor(cs1, 32);
    cs2 += __shfl_xor(cs2, 1); cs2 += __shfl_xor(cs2, 2);
    cs2 += __shfl_xor(cs2, 4); cs2 += __shfl_xor(cs2, 8);
    cs2 += __shfl_xor(cs2, 16); cs2 += __shfl_xor(cs2, 32);
    if (lane == 0) {
        csw[wave * 3 + 0] = cs0;
        csw[wave * 3 + 1] = cs1;
        csw[wave * 3 + 2] = cs2;
    }
#pragma unroll
    for (int rg = 0; rg < 4; ++rg) {
        float v = agg0[rg];
        v += __shfl_xor(v, 1); v += __shfl_xor(v, 2);
        v += __shfl_xor(v, 4); v += __shfl_xor(v, 8);
        agg0[rg] = v;
        float u = agg1[rg];
        u += __shfl_xor(u, 1); u += __shfl_xor(u, 2);
        u += __shfl_xor(u, 4); u += __shfl_xor(u, 8);
        agg1[rg] = u;
    }
    if (l15 == 0) {
        *(floatx4*)(aggs + wg * 32 + q * 4)      = agg0;
        *(floatx4*)(aggs + wg * 32 + 16 + q * 4) = agg1;
    }
    __syncthreads();
    if (tid < F_) aggt[tid] = aggs[tid] * mask_i;
    __syncthreads();
    // ---- node MLP layer 1 ----
    {
        int half = tid >> 7, col = tid & 127;
        const float* W = nw1 + half * 128 * F_ + col;
        float s = 0.f;
        if (half == 0) {
#pragma unroll 8
            for (int k = 0; k < F_; ++k) s += hin[k] * W[k * F_];
            s *= mask_i;
        } else {
#pragma unroll 8
            for (int k = 0; k < F_; ++k) s += aggt[k] * W[k * F_];
        }
        np[tid] = s;
    }
    __syncthreads();
    if (tid < F_) tl[tid] = fsilu(np[tid] + np[128 + tid] + nb1[tid]);
    __syncthreads();
    if (tid < F_) {
        float s = nb2[tid];
#pragma unroll 8
        for (int k = 0; k < F_; ++k) s += tl[k] * nw2[k * F_ + tid];
        out_h[bi * F_ + tid] = (hin[tid] + s) * mask_i;
    } else if (tid < F_ + 3) {
        int d = tid - F_;
        float cs = csw[d] + csw[3 + d] + csw[6 + d] + csw[9 + d];
        float denom = mask_i * msum[b] + 1e-10f;
        float cm = (d == 0) ? cmi0 : ((d == 1) ? cmi1 : cmi2);
        out_coord[bi * 3 + d] = (cm + cs * __builtin_amdgcn_rcpf(denom)) * mask_i;
    }
}

// ---------------------------------------------------------------------------
extern "C" void kernel_launch(void* const* d_in, const int* in_sizes, int n_in,
                              void* d_out, int out_size, void* d_ws, size_t ws_size,
                              hipStream_t stream) {
    const float* h     = (const float*)d_in[0];
    const float* coord = (const float*)d_in[1];
    const float* mask  = (const float*)d_in[2];
    const float* ew1   = (const float*)d_in[3];
    const float* eb1   = (const float*)d_in[4];
    const float* ew2   = (const float*)d_in[5];
    const float* eb2   = (const float*)d_in[6];
    const float* nw1   = (const float*)d_in[7];
    const float* nb1   = (const float*)d_in[8];
    const float* nw2   = (const float*)d_in[9];
    const float* nb2   = (const float*)d_in[10];
    const float* cw1   = (const float*)d_in[11];
    const float* cb1   = (const float*)d_in[12];
    const float* cw2   = (const float*)d_in[13];

    float* Hs = (float*)d_ws;                                   // 131072 f32
    float* Ht = Hs + B_ * N_ * F_;                              // 131072 f32
    unsigned short* W2P = (unsigned short*)(Ht + B_ * N_ * F_); // 16384 u16
    unsigned short* WcP = W2P + F_ * F_;                        // 16384 u16
    float* msum = (float*)(WcP + F_ * F_);                      // 2 f32

    float* out_h = (float*)d_out;
    float* out_coord = out_h + B_ * N_ * F_;

    egcl_prep<<<146, 256, 0, stream>>>(h, mask, ew1, ew2, cw1,
                                       Hs, Ht, W2P, WcP, msum);
    egcl_main<<<B_ * N_, 256, L_TOTAL, stream>>>(
        h, coord, mask, eb1, eb2, cb1, cw2, nw1, nb1, nw2, nb2, ew1,
        Hs, Ht, W2P, WcP, msum, out_h, out_coord);
}

// Round 12
// 179.162 us; speedup vs baseline: 1.0288x; 1.0288x over previous
//
#include <hip/hip_runtime.h>

// ============================================================================
// FINAL (R12) = R7 verbatim — best measured: total 180.67 µs, main ~107 µs.
//
// Session plateau evidence (main-kernel dur / VALUBusy / MfmaUtil):
//   R7  256t TJ64 3-barrier            : 107 µs / 54% / 12.8%   <- best
//   R8  256t TJ32 2-barrier            : 115 µs / 51% / 12.0%
//   R9  512t TJ64 2-barrier            : 128 µs / 46% / 10.8%
//   R10 256t TJ64 2-barrier (embp-N)   : 113 µs / 52% / 12.4%
//   R11 256t TJ64 1-barrier pipelined  : 113 µs / 56% / 12.6%
// VALU-busy time is ~59 µs in ALL variants -> issue-bound floor of this
// decomposition (201M silu = 402M quarter-rate trans ops is the algorithm);
// the residual stall is dependency latency at ~2 resident waves/SIMD and
// survived barrier-count, TLP, and software-pipelining interventions.
// ============================================================================

#define B_ 2
#define N_ 512
#define F_ 128
#define TJ 64       // j-rows per tile
#define MSTRIDE 136 // shorts per LDS row: 128 + 8 pad (16B-aligned rows)

typedef __attribute__((ext_vector_type(8))) short short8;
typedef __attribute__((ext_vector_type(4))) float floatx4;

__device__ __forceinline__ float fsilu(float x) {
    float e = __expf(-x);
    return x * __builtin_amdgcn_rcpf(1.0f + e);
}
// pack two floats to bf16 pair via v_perm_b32
__device__ __forceinline__ unsigned pack2(float a, float b) {
    return __builtin_amdgcn_perm(__float_as_uint(b) + 0x8000u,
                                 __float_as_uint(a) + 0x8000u, 0x07060302u);
}

// ---------------------------------------------------------------------------
// Prep: blocks [0,128): Hs/Ht (8 rows each); [128,144): weight A-frag pack;
//       [144,146): msum.
// ---------------------------------------------------------------------------
__global__ __launch_bounds__(256) void egcl_prep(
        const float* __restrict__ h, const float* __restrict__ mask,
        const float* __restrict__ ew1, const float* __restrict__ ew2,
        const float* __restrict__ cw1,
        float* __restrict__ Hs, float* __restrict__ Ht,
        unsigned short* __restrict__ W2P, unsigned short* __restrict__ WcP,
        float* __restrict__ msum) {
    __shared__ float sh[8][F_];
    const int blk = blockIdx.x, tid = threadIdx.x;
    if (blk < 128) {
        const int r0 = blk * 8;
        const int col = tid & 127, half = tid >> 7;
#pragma unroll
        for (int rr = 0; rr < 4; ++rr) {
            int row = rr * 2 + half;
            sh[row][col] = h[(r0 + row) * F_ + col] * mask[r0 + row];
        }
        __syncthreads();
        const float* W = ew1 + half * F_ * F_ + col;
        float acc[8] = {0.f, 0.f, 0.f, 0.f, 0.f, 0.f, 0.f, 0.f};
#pragma unroll 8
        for (int k = 0; k < F_; ++k) {
            float w = W[k * F_];
#pragma unroll
            for (int r = 0; r < 8; ++r) acc[r] += sh[r][k] * w;
        }
        float* dst = half ? Ht : Hs;
#pragma unroll
        for (int r = 0; r < 8; ++r) dst[(r0 + r) * F_ + col] = acc[r];
    } else if (blk < 144) {
        const int wsel = (blk - 128) >> 3;
        const int mt = (blk - 128) & 7;
        const float* src = wsel ? cw1 : ew2;
        unsigned short* dst = wsel ? WcP : W2P;
        const int ln = tid & 63, kk = tid >> 6;       // kk 0..3
        const int qq = ln >> 4, ll = ln & 15;
#pragma unroll
        for (int rep = 0; rep < 2; ++rep) {
            const int krow = kk * 32 + qq * 8 + rep * 4;
            float f0 = src[(krow + 0) * F_ + mt * 16 + ll];
            float f1 = src[(krow + 1) * F_ + mt * 16 + ll];
            float f2 = src[(krow + 2) * F_ + mt * 16 + ll];
            float f3 = src[(krow + 3) * F_ + mt * 16 + ll];
            uint2 u = make_uint2(pack2(f0, f1), pack2(f2, f3));
            *(uint2*)(dst + ((mt * 4 + kk) * 64 + ln) * 8 + rep * 4) = u;
        }
    } else {
        const int bb = blk - 144;
        float v = mask[bb * N_ + tid] + mask[bb * N_ + 256 + tid];
        v += __shfl_xor(v, 1);  v += __shfl_xor(v, 2);
        v += __shfl_xor(v, 4);  v += __shfl_xor(v, 8);
        v += __shfl_xor(v, 16); v += __shfl_xor(v, 32);
        const int wave = tid >> 6, lane = tid & 63;
        if (lane == 0) sh[0][wave] = v;
        __syncthreads();
        if (tid == 0) msum[bb] = sh[0][0] + sh[0][1] + sh[0][2] + sh[0][3];
    }
}

// LDS layout (bytes) — total 39.0 KB.
#define L_M1   0        // 64*136*2 = 17408
#define L_M    17408    // 17408
#define L_HB   34816    // 512
#define L_W1R  35328    // 512
#define L_EMBP 35840    // 4*64*4 = 1024
#define L_AGG  36864    // 512
#define L_HIN  37376    // 512
#define L_AGGT 37888    // 512
#define L_TL   38400    // 512
#define L_NP   38912    // 1024
#define L_CSW  39936    // 32
#define L_TOTAL 39968

// ---------------------------------------------------------------------------
// Main: 1024 blocks x 256 threads (4 waves); block = one (b,i). Wave wg owns
// fo slice [wg*32, wg*32+32) with weights in registers as MFMA A-operands
// (2 MFMAs per LDS b128 activation read). j in 8 tiles of 64 rows; 3
// barriers per tile. Key verified facts:
//  - GEMM1 output D[fo][j] (fo = quad*4+reg) packs directly as GEMM2's
//    B-operand rows -> uint2 LDS writes, no transpose pass.
//  - edge_w1 GEMM decomposed as Hs[j]+Ht[i]+radial*w1_row (prep kernel),
//    deleting 2/3 of edge-MLP FLOPs.
//
// __launch_bounds__ 2nd-arg EMPIRICAL RULE (this toolchain, gfx950):
//   (512,4)/(256,4) -> 64-VGPR cap, catastrophic spill (R4/R6: 323-371 MB
//   FETCH). (512,2)/(256,2) -> no harmful cap (R5: 124, R7: 100 VGPR).
//   NEVER set the 2nd arg >= 4 for this kernel.
// ---------------------------------------------------------------------------
__global__ __launch_bounds__(256, 2) void egcl_main(
        const float* __restrict__ h, const float* __restrict__ coord,
        const float* __restrict__ mask,
        const float* __restrict__ eb1, const float* __restrict__ eb2,
        const float* __restrict__ cb1, const float* __restrict__ cw2,
        const float* __restrict__ nw1, const float* __restrict__ nb1,
        const float* __restrict__ nw2, const float* __restrict__ nb2,
        const float* __restrict__ ew1,
        const float* __restrict__ Hs, const float* __restrict__ Ht,
        const unsigned short* __restrict__ W2P,
        const unsigned short* __restrict__ WcP,
        const float* __restrict__ msum,
        float* __restrict__ out_h, float* __restrict__ out_coord) {
    extern __shared__ char smem[];
    unsigned short* m1s = (unsigned short*)(smem + L_M1);
    unsigned short* ms  = (unsigned short*)(smem + L_M);
    float* HB    = (float*)(smem + L_HB);
    float* W1R   = (float*)(smem + L_W1R);
    float* embp  = (float*)(smem + L_EMBP);
    float* aggs  = (float*)(smem + L_AGG);
    float* hin   = (float*)(smem + L_HIN);
    float* aggt  = (float*)(smem + L_AGGT);
    float* tl    = (float*)(smem + L_TL);
    float* np    = (float*)(smem + L_NP);
    float* csw   = (float*)(smem + L_CSW);

    const int tid  = threadIdx.x;
    const int wave = tid >> 6, lane = tid & 63;
    const int q = lane >> 4, l15 = lane & 15;
    const int wg = wave;                 // fo slice [wg*32, wg*32+32)
    const int bi = blockIdx.x;
    const int b  = bi >> 9;
    const float mask_i = mask[bi];

    // per-wave weight A-fragments (2 mt-slices of 16 fo each)
    short8 w2f[2][4], wcf[2][4];
#pragma unroll
    for (int s = 0; s < 2; ++s)
#pragma unroll
        for (int kk = 0; kk < 4; ++kk) {
            w2f[s][kk] = *(const short8*)(W2P + (((2 * wg + s) * 4 + kk) * 64 + lane) * 8);
            wcf[s][kk] = *(const short8*)(WcP + (((2 * wg + s) * 4 + kk) * 64 + lane) * 8);
        }
    floatx4 e2b[2], c1b[2], w2c[2];
#pragma unroll
    for (int s = 0; s < 2; ++s) {
        e2b[s] = *(const floatx4*)(eb2 + wg * 32 + s * 16 + q * 4);
        c1b[s] = *(const floatx4*)(cb1 + wg * 32 + s * 16 + q * 4);
        w2c[s] = *(const floatx4*)(cw2 + wg * 32 + s * 16 + q * 4);
    }

    if (tid < F_) {
        HB[tid]  = Ht[bi * F_ + tid] + eb1[tid];
        W1R[tid] = ew1[2 * F_ * F_ + tid];
        hin[tid] = h[bi * F_ + tid] * mask_i;
    }
    const float cmi0 = coord[bi * 3 + 0] * mask_i;
    const float cmi1 = coord[bi * 3 + 1] * mask_i;
    const float cmi2 = coord[bi * 3 + 2] * mask_i;
    __syncthreads();

    const int kseg = tid & 15, jq = tid >> 4;  // jq in [0,16)
    float hbk[8], w1k[8];
    {
        const floatx4* hp = (const floatx4*)(HB + kseg * 8);
        const floatx4* wp = (const floatx4*)(W1R + kseg * 8);
        floatx4 a = hp[0], bb2 = hp[1], cc = wp[0], dd = wp[1];
#pragma unroll
        for (int t = 0; t < 4; ++t) {
            hbk[t] = a[t]; hbk[4 + t] = bb2[t];
            w1k[t] = cc[t]; w1k[4 + t] = dd[t];
        }
    }
    floatx4 agg0 = {0.f, 0.f, 0.f, 0.f}, agg1 = {0.f, 0.f, 0.f, 0.f};
    float cs0 = 0.f, cs1 = 0.f, cs2 = 0.f;

    for (int p = 0; p < N_ / TJ; ++p) {
        // ---- m1 build: each thread covers 4 rows x 8 k ----
#pragma unroll
        for (int r = 0; r < 4; ++r) {
            int row = jq * 4 + r;
            int jg = b * N_ + p * TJ + row;
            float mj = mask[jg];
            float c0 = coord[jg * 3 + 0] * mj;
            float c1 = coord[jg * 3 + 1] * mj;
            float c2 = coord[jg * 3 + 2] * mj;
            float d0 = cmi0 - c0, d1 = cmi1 - c1, d2 = cmi2 - c2;
            float f2 = mask_i * mj;
            float rad = (d0 * d0 + d1 * d1 + d2 * d2) * f2;
            const floatx4* hsp = (const floatx4*)(Hs + jg * F_ + kseg * 8);
            floatx4 h0 = hsp[0], h1 = hsp[1];
            float x[8];
#pragma unroll
            for (int t = 0; t < 4; ++t) {
                x[t]     = fsilu(h0[t] + hbk[t]     + rad * w1k[t]);
                x[4 + t] = fsilu(h1[t] + hbk[4 + t] + rad * w1k[4 + t]);
            }
            union { short8 s8; unsigned u[4]; } pu;
            pu.u[0] = pack2(x[0], x[1]); pu.u[1] = pack2(x[2], x[3]);
            pu.u[2] = pack2(x[4], x[5]); pu.u[3] = pack2(x[6], x[7]);
            *(short8*)(m1s + row * MSTRIDE + kseg * 8) = pu.s8;
        }
        __syncthreads();
        // ---- GEMM1 (weights-in-regs as A) + epilogue1 ----
#pragma unroll
        for (int jt = 0; jt < 4; ++jt) {
            const int jrow = jt * 16 + l15;
            const unsigned short* m1r = m1s + jrow * MSTRIDE;
            floatx4 a0 = e2b[0], a1 = e2b[1];  // bias-init
#pragma unroll
            for (int kk = 0; kk < 4; ++kk) {
                short8 bf = *(const short8*)(m1r + kk * 32 + q * 8);
                a0 = __builtin_amdgcn_mfma_f32_16x16x32_bf16(w2f[0][kk], bf, a0, 0, 0, 0);
                a1 = __builtin_amdgcn_mfma_f32_16x16x32_bf16(w2f[1][kk], bf, a1, 0, 0, 0);
            }
            const float f2 = mask_i * mask[b * N_ + p * TJ + jrow];
            float v0[4], v1[4];
#pragma unroll
            for (int rg = 0; rg < 4; ++rg) {
                v0[rg] = fsilu(a0[rg]) * f2;
                v1[rg] = fsilu(a1[rg]) * f2;
                agg0[rg] += v0[rg];
                agg1[rg] += v1[rg];
            }
            unsigned short* mr = ms + jrow * MSTRIDE + wg * 32 + q * 4;
            *(uint2*)(mr)      = make_uint2(pack2(v0[0], v0[1]), pack2(v0[2], v0[3]));
            *(uint2*)(mr + 16) = make_uint2(pack2(v1[0], v1[1]), pack2(v1[2], v1[3]));
        }
        __syncthreads();
        // ---- GEMM2 + embed partials ----
#pragma unroll
        for (int jt = 0; jt < 4; ++jt) {
            const int jrow = jt * 16 + l15;
            const unsigned short* mr = ms + jrow * MSTRIDE;
            floatx4 a0 = c1b[0], a1 = c1b[1];
#pragma unroll
            for (int kk = 0; kk < 4; ++kk) {
                short8 bf = *(const short8*)(mr + kk * 32 + q * 8);
                a0 = __builtin_amdgcn_mfma_f32_16x16x32_bf16(wcf[0][kk], bf, a0, 0, 0, 0);
                a1 = __builtin_amdgcn_mfma_f32_16x16x32_bf16(wcf[1][kk], bf, a1, 0, 0, 0);
            }
            float es = 0.f;
#pragma unroll
            for (int rg = 0; rg < 4; ++rg) {
                es += fsilu(a0[rg]) * w2c[0][rg];
                es += fsilu(a1[rg]) * w2c[1][rg];
            }
            es += __shfl_xor(es, 16);
            es += __shfl_xor(es, 32);
            if (q == 0) embp[wg * 64 + jrow] = es;
        }
        __syncthreads();
        // ---- coord accumulation (threads 0..63 = wave 0) ----
        if (tid < TJ) {
            float e = embp[tid] + embp[64 + tid] + embp[128 + tid] + embp[192 + tid];
            int jg = b * N_ + p * TJ + tid;
            float mj = mask[jg];
            float c0 = coord[jg * 3 + 0] * mj;
            float c1 = coord[jg * 3 + 1] * mj;
            float c2 = coord[jg * 3 + 2] * mj;
            float f2 = mask_i * mj;
            float w = e * f2 * f2;
            cs0 += (cmi0 - c0) * w;
            cs1 += (cmi1 - c1) * w;
            cs2 += (cmi2 - c2) * w;
        }
    }  // p

    // ---- reductions ----
#pragma unroll
    for (int rg = 0; rg < 4; ++rg) {
        float v = agg0[rg];
        v += __shfl_xor(v, 1); v += __shfl_xor(v, 2);
        v += __shfl_xor(v, 4); v += __shfl_xor(v, 8);
        agg0[rg] = v;
        float u = agg1[rg];
        u += __shfl_xor(u, 1); u += __shfl_xor(u, 2);
        u += __shfl_xor(u, 4); u += __shfl_xor(u, 8);
        agg1[rg] = u;
    }
    if (l15 == 0) {
        *(floatx4*)(aggs + wg * 32 + q * 4)      = agg0;
        *(floatx4*)(aggs + wg * 32 + 16 + q * 4) = agg1;
    }
    if (wave == 0) {
        cs0 += __shfl_xor(cs0, 1); cs0 += __shfl_xor(cs0, 2);
        cs0 += __shfl_xor(cs0, 4); cs0 += __shfl_xor(cs0, 8);
        cs0 += __shfl_xor(cs0, 16); cs0 += __shfl_xor(cs0, 32);
        cs1 += __shfl_xor(cs1, 1); cs1 += __shfl_xor(cs1, 2);
        cs1 += __shfl_xor(cs1, 4); cs1 += __shfl_xor(cs1, 8);
        cs1 += __shfl_xor(cs1, 16); cs1 += __shfl_xor(cs1, 32);
        cs2 += __shfl_xor(cs2, 1); cs2 += __shfl_xor(cs2, 2);
        cs2 += __shfl_xor(cs2, 4); cs2 += __shfl_xor(cs2, 8);
        cs2 += __shfl_xor(cs2, 16); cs2 += __shfl_xor(cs2, 32);
        if (lane == 0) {
            csw[0] = cs0; csw[1] = cs1; csw[2] = cs2;
        }
    }
    __syncthreads();
    if (tid < F_) aggt[tid] = aggs[tid] * mask_i;
    __syncthreads();
    // ---- node MLP layer 1 ----
    {
        int half = tid >> 7, col = tid & 127;
        const float* W = nw1 + half * 128 * F_ + col;
        float s = 0.f;
        if (half == 0) {
#pragma unroll 8
            for (int k = 0; k < F_; ++k) s += hin[k] * W[k * F_];
            s *= mask_i;
        } else {
#pragma unroll 8
            for (int k = 0; k < F_; ++k) s += aggt[k] * W[k * F_];
        }
        np[tid] = s;
    }
    __syncthreads();
    if (tid < F_) tl[tid] = fsilu(np[tid] + np[128 + tid] + nb1[tid]);
    __syncthreads();
    if (tid < F_) {
        float s = nb2[tid];
#pragma unroll 8
        for (int k = 0; k < F_; ++k) s += tl[k] * nw2[k * F_ + tid];
        out_h[bi * F_ + tid] = (hin[tid] + s) * mask_i;
    } else if (tid < F_ + 3) {
        int d = tid - F_;
        float denom = mask_i * msum[b] + 1e-10f;
        float cm = (d == 0) ? cmi0 : ((d == 1) ? cmi1 : cmi2);
        out_coord[bi * 3 + d] = (cm + csw[d] * __builtin_amdgcn_rcpf(denom)) * mask_i;
    }
}

// ---------------------------------------------------------------------------
extern "C" void kernel_launch(void* const* d_in, const int* in_sizes, int n_in,
                              void* d_out, int out_size, void* d_ws, size_t ws_size,
                              hipStream_t stream) {
    const float* h     = (const float*)d_in[0];
    const float* coord = (const float*)d_in[1];
    const float* mask  = (const float*)d_in[2];
    const float* ew1   = (const float*)d_in[3];
    const float* eb1   = (const float*)d_in[4];
    const float* ew2   = (const float*)d_in[5];
    const float* eb2   = (const float*)d_in[6];
    const float* nw1   = (const float*)d_in[7];
    const float* nb1   = (const float*)d_in[8];
    const float* nw2   = (const float*)d_in[9];
    const float* nb2   = (const float*)d_in[10];
    const float* cw1   = (const float*)d_in[11];
    const float* cb1   = (const float*)d_in[12];
    const float* cw2   = (const float*)d_in[13];

    float* Hs = (float*)d_ws;                                   // 131072 f32
    float* Ht = Hs + B_ * N_ * F_;                              // 131072 f32
    unsigned short* W2P = (unsigned short*)(Ht + B_ * N_ * F_); // 16384 u16
    unsigned short* WcP = W2P + F_ * F_;                        // 16384 u16
    float* msum = (float*)(WcP + F_ * F_);                      // 2 f32

    float* out_h = (float*)d_out;
    float* out_coord = out_h + B_ * N_ * F_;

    egcl_prep<<<146, 256, 0, stream>>>(h, mask, ew1, ew2, cw1,
                                       Hs, Ht, W2P, WcP, msum);
    egcl_main<<<B_ * N_, 256, L_TOTAL, stream>>>(
        h, coord, mask, eb1, eb2, cb1, cw2, nw1, nb1, nw2, nb2, ew1,
        Hs, Ht, W2P, WcP, msum, out_h, out_coord);
}